// Round 26
// baseline (54.810 us; speedup 1.0000x reference)
//
#include <hip/hip_runtime.h>
#include <hip/hip_bf16.h>

// Flash attention fwd, causal + key-padding, B=4 S=4096 D=64, fp32 in/out.
// Round 26: round-25 base (48.4us, CL=6) + V-fragment hoist retry:
//  - per kt, the 4 PV A-fragments (now ONE b128 load each, thanks to the
//    permuted V^T layout) are loaded BEFORE mask/softmax, hiding their
//    lgkm latency under the ~400cy softmax VALU chain.
//  - __launch_bounds__(256,2) (was 3): round 19's identical hoist spilled
//    ONLY because the (256,3) bound capped regs (~85); +16 transient VGPR
//    now fits (<128). Residency unaffected: LDS allows 9 blocks/CU and
//    measured occupancy is ~2.9. Spill tripwire: WRITE_SIZE (not VGPR col).

#define S_LEN 4096
#define D_DIM 64
#define NBATCH 4
#define QBLK 128
#define KVBLK 64
#define NQB (S_LEN / QBLK)          // 32 q-blocks per batch
#define SLOT_B 17408                // 16K bf16 O + 1K fp32 m/l

typedef __attribute__((ext_vector_type(16))) float f32x16;
typedef __attribute__((ext_vector_type(4))) float f32x4;
typedef __attribute__((ext_vector_type(8))) short s16x8;
typedef __attribute__((ext_vector_type(4))) short s16x4;
typedef __attribute__((ext_vector_type(2))) unsigned int u32x2;

#define FK(n) ((((n) ^ ((n) >> 3)) & 7) << 4)   // row swizzle (K and V^T)

__device__ __forceinline__ unsigned short f2bfu(float f) {
  return __builtin_bit_cast(unsigned short, __float2bfloat16(f));
}
__device__ __forceinline__ unsigned pk2(float a, float b) {
  return (unsigned)f2bfu(a) | ((unsigned)f2bfu(b) << 16);
}
__device__ __forceinline__ float bf2f(short s) {
  return __builtin_bit_cast(float, ((unsigned)(unsigned short)s) << 16);
}

__global__ __launch_bounds__(256, 2) void fattn_partial(
    const float* __restrict__ Qg, const float* __restrict__ Kg,
    const float* __restrict__ Vg, const unsigned char* __restrict__ Pad,
    char* __restrict__ Ws, int CL, int TOTC)
{
  // Uniform partition: enumeration index u -> (Qb, ci); heavy-first.
  const int wid = blockIdx.x;
  const int b   = wid & 3;
  const int u   = TOTC - 1 - (wid >> 2);
  int Qb = 0, ci = 0;
  {
    int uu = u, q = 0;
    while (true) {
      const int nch = (2 * q + 2 + CL - 1) / CL;
      if (uu < nch) { ci = uu; break; }
      uu -= nch; ++q;
    }
    Qb = q;
  }
  const int q0  = Qb * QBLK;
  const int ntt = 2 * Qb + 2;
  const int t0  = ci * CL;
  const int t1  = (t0 + CL < ntt) ? (t0 + CL) : ntt;

  const int tid = threadIdx.x;
  const int w   = tid >> 6;          // wave 0..3 -> q rows [q0+32w, q0+32w+32)
  const int l   = tid & 63;
  const int ql  = l & 31;
  const int hi  = l >> 5;
  const int qw0 = q0 + 32 * w;
  const int qa  = qw0 + ql;

  // K staging roles (64 rows x 16-float windows over 256 threads)
  const int sq  = l & 3;
  const int sm  = (l >> 2) & 3;
  const int sc2 = l >> 4;
  const int snb = 4 * w + 16 * sc2;  // n-chunk base (multiple of 4)
  // V staging roles: one 4x4 block per thread (in-lane transpose)
  const int vn0 = (tid & 15) << 2;   // V rows (k values) [vn0, vn0+4)
  const int vd0 = (tid >> 4) << 2;   // V cols (d values) [vd0, vd0+4)
  // k->position permutation: swap 4-groups 1<->2 within each 16-group
  const int pvn0 = (vn0 & 48) | (((vn0 & 4) << 1) | ((vn0 & 8) >> 1));

  __shared__ __align__(16) short Ksh[KVBLK * D_DIM];   // [n][d], FK-swizzled
  __shared__ __align__(16) short Vtsh[D_DIM * KVBLK];  // [d][perm k], FK-swz
  __shared__ int anyPadSh;

  const size_t bS = (size_t)b * S_LEN;
  const unsigned char* PadB = Pad + bS;

  // ---- prologue: block-wide padding flag for this chunk's key range ----
  if (tid == 0) anyPadSh = 0;
  __syncthreads();
  {
    const int nk  = (t1 - t0) * KVBLK;      // <= 512
    const int idx = 2 * tid;
    if (idx < nk) {
      const unsigned char* pp = PadB + t0 * KVBLK + idx;
      const bool nz = pp[0] || ((idx + 1 < nk) ? pp[1] : (unsigned char)0);
      if (nz) anyPadSh = 1;                 // benign same-value race
    }
  }

  // ---- Q fragments (B-operand), pre-scaled by 1/8 ----
  s16x8 qf[4];
  {
    const float* qp = Qg + (bS + qa) * D_DIM + 8 * hi;
    #pragma unroll
    for (int dc = 0; dc < 4; ++dc)
      #pragma unroll
      for (int j = 0; j < 8; ++j)
        qf[dc][j] = (short)f2bfu(qp[16 * dc + j] * 0.125f);
  }

  f32x16 acc[2];
  #pragma unroll
  for (int dt = 0; dt < 2; ++dt)
    #pragma unroll
    for (int i = 0; i < 16; ++i) acc[dt][i] = 0.f;
  float mrow = -INFINITY;
  float lrow = 0.f;

  u32x2 kpb[4], vpb[4];   // bf16-packed prefetch; vpb already transposed

#define LOAD_KV(T) do {                                                      \
    const int kv0_ = (T) * KVBLK;                                            \
    _Pragma("unroll")                                                        \
    for (int s_ = 0; s_ < 4; ++s_) {                                         \
      const size_t go_ =                                                     \
          (bS + kv0_ + snb + sq) * D_DIM + 16 * s_ + 4 * sm;                 \
      const float4 kx = *(const float4*)(Kg + go_);                          \
      kpb[s_][0] = pk2(kx.x, kx.y); kpb[s_][1] = pk2(kx.z, kx.w);            \
    }                                                                        \
    const float* vp_ = Vg + (bS + kv0_ + vn0) * D_DIM + vd0;                 \
    const float4 r0 = *(const float4*)(vp_);                                 \
    const float4 r1 = *(const float4*)(vp_ + D_DIM);                         \
    const float4 r2 = *(const float4*)(vp_ + 2 * D_DIM);                     \
    const float4 r3 = *(const float4*)(vp_ + 3 * D_DIM);                     \
    const float* f0 = (const float*)&r0; const float* f1 = (const float*)&r1;\
    const float* f2 = (const float*)&r2; const float* f3 = (const float*)&r3;\
    _Pragma("unroll")                                                        \
    for (int j_ = 0; j_ < 4; ++j_) {                                         \
      vpb[j_][0] = pk2(f0[j_], f1[j_]);                                      \
      vpb[j_][1] = pk2(f2[j_], f3[j_]);                                      \
    }                                                                        \
  } while (0)

#define STAGE() do {                                                         \
    _Pragma("unroll")                                                        \
    for (int s_ = 0; s_ < 4; ++s_) {                                         \
      const int d0_ = 16 * s_ + 4 * sm; const int nk_ = snb + sq;            \
      *(u32x2*)((char*)&Ksh[0] + nk_ * 128 + ((2 * d0_) ^ FK(nk_))) =        \
          kpb[s_];                                                           \
      const int dv_ = vd0 + s_;                                              \
      *(u32x2*)((char*)&Vtsh[0] + dv_ * 128 + ((2 * pvn0) ^ FK(dv_))) =      \
          vpb[s_];                                                           \
    }                                                                        \
  } while (0)

  LOAD_KV(t0);

  for (int t = t0; t < t1; ++t) {
    STAGE();                          // write prefetched tile to LDS
    __syncthreads();                  // staging visible to all waves
    const bool more = (t + 1 < t1);
    if (more) LOAD_KV(t + 1);         // prefetch next tile into regs

    const int kv0 = t * KVBLK;

    // ---- BOTH QK^T clusters first (sm(0) overlaps QK(1) latency) ----
    f32x16 sv0, sv1;
    __builtin_amdgcn_s_setprio(1);
    {
      f32x16 a;
      #pragma unroll
      for (int i = 0; i < 16; ++i) a[i] = 0.f;
      #pragma unroll
      for (int dc = 0; dc < 4; ++dc) {
        const int nr = ql;
        const s16x8 kf = *(const s16x8*)((char*)&Ksh[0] + nr * 128 +
                                         ((32 * dc + 16 * hi) ^ FK(nr)));
        a = __builtin_amdgcn_mfma_f32_32x32x16_bf16(kf, qf[dc], a, 0, 0, 0);
      }
      sv0 = a;
    }
    {
      f32x16 a;
      #pragma unroll
      for (int i = 0; i < 16; ++i) a[i] = 0.f;
      #pragma unroll
      for (int dc = 0; dc < 4; ++dc) {
        const int nr = 32 + ql;
        const s16x8 kf = *(const s16x8*)((char*)&Ksh[0] + nr * 128 +
                                         ((32 * dc + 16 * hi) ^ FK(nr)));
        a = __builtin_amdgcn_mfma_f32_32x32x16_bf16(kf, qf[dc], a, 0, 0, 0);
      }
      sv1 = a;
    }
    __builtin_amdgcn_s_setprio(0);

    // ---- per-32k subtile: V-preload -> mask -> softmax -> PV ----
    #pragma unroll
    for (int kt = 0; kt < 2; ++kt) {
      // V fragments hoisted above softmax: one b128 load each (permuted
      // layout), lgkm latency hides under the softmax VALU chain.
      s16x8 vfr0_0, vfr0_1, vfr1_0, vfr1_1;
      {
        const int sk0 = 2 * kt, sk1 = 2 * kt + 1;
        const int dr0 = ql, dr1 = 32 + ql;
        vfr0_0 = *(const s16x8*)((char*)&Vtsh[0] + dr0 * 128 +
                                 ((32 * sk0 + 16 * hi) ^ FK(dr0)));
        vfr0_1 = *(const s16x8*)((char*)&Vtsh[0] + dr1 * 128 +
                                 ((32 * sk0 + 16 * hi) ^ FK(dr1)));
        vfr1_0 = *(const s16x8*)((char*)&Vtsh[0] + dr0 * 128 +
                                 ((32 * sk1 + 16 * hi) ^ FK(dr0)));
        vfr1_1 = *(const s16x8*)((char*)&Vtsh[0] + dr1 * 128 +
                                 ((32 * sk1 + 16 * hi) ^ FK(dr1)));
      }

      f32x16 sv = (kt == 0) ? sv0 : sv1;
      const int kvt = kv0 + 32 * kt;
      // padding (rare path)
      if (anyPadSh) {
        #pragma unroll
        for (int r1 = 0; r1 < 4; ++r1) {
          const unsigned pd =
              *(const unsigned*)(PadB + kvt + 8 * r1 + 4 * hi);
          #pragma unroll
          for (int r0 = 0; r0 < 4; ++r0)
            if ((pd >> (8 * r0)) & 0xFFu) sv[4 * r1 + r0] = -1e30f;
        }
      }
      // causal mask (diagonal band only): k = kvt+8r1+4hi+r0
      if (kvt + 31 > qw0) {
        #pragma unroll
        for (int r1 = 0; r1 < 4; ++r1)
          #pragma unroll
          for (int r0 = 0; r0 < 4; ++r0)
            if (kvt + 8 * r1 + 4 * hi + r0 > qa) sv[4 * r1 + r0] = -1e30f;
      }

      // online softmax step (tree max, 4-way sum)
      f32x4 m4;
      #pragma unroll
      for (int i = 0; i < 4; ++i)
        m4[i] = fmaxf(fmaxf(sv[i], sv[i + 4]), fmaxf(sv[i + 8], sv[i + 12]));
      float vm = fmaxf(fmaxf(m4[0], m4[1]), fmaxf(m4[2], m4[3]));
      vm = fmaxf(vm, __shfl_xor(vm, 32));         // merge across hi halves
      const float mn   = fmaxf(mrow, vm);
      const float corr = __expf(mrow - mn);
      mrow = mn;
      lrow *= corr;
      #pragma unroll
      for (int dt = 0; dt < 2; ++dt)
        #pragma unroll
        for (int i = 0; i < 16; ++i) acc[dt][i] *= corr;

      float rs0 = 0.f, rs1 = 0.f, rs2 = 0.f, rs3 = 0.f;
      #pragma unroll
      for (int i4 = 0; i4 < 16; i4 += 4) {
        const float p0 = __expf(sv[i4 + 0] - mn);
        const float p1 = __expf(sv[i4 + 1] - mn);
        const float p2 = __expf(sv[i4 + 2] - mn);
        const float p3 = __expf(sv[i4 + 3] - mn);
        sv[i4 + 0] = p0; sv[i4 + 1] = p1;
        sv[i4 + 2] = p2; sv[i4 + 3] = p3;
        rs0 += p0; rs1 += p1; rs2 += p2; rs3 += p3;
      }
      lrow += (rs0 + rs1) + (rs2 + rs3);          // own half-sum only

      // O^T += mfma(A=V^T, B=P): fragments already in registers
      __builtin_amdgcn_s_setprio(1);
      #pragma unroll
      for (int sh = 0; sh < 2; ++sh) {
        const int rb = 8 * sh;
        union { unsigned uu[4]; s16x8 v; } pb;
        pb.uu[0] = pk2(sv[rb + 0], sv[rb + 1]);
        pb.uu[1] = pk2(sv[rb + 2], sv[rb + 3]);
        pb.uu[2] = pk2(sv[rb + 4], sv[rb + 5]);
        pb.uu[3] = pk2(sv[rb + 6], sv[rb + 7]);
        acc[0] = __builtin_amdgcn_mfma_f32_32x32x16_bf16(
            (sh == 0) ? vfr0_0 : vfr1_0, pb.v, acc[0], 0, 0, 0);
        acc[1] = __builtin_amdgcn_mfma_f32_32x32x16_bf16(
            (sh == 0) ? vfr0_1 : vfr1_1, pb.v, acc[1], 0, 0, 0);
      }
      __builtin_amdgcn_s_setprio(0);
    }

    __syncthreads();                  // all waves done reading before restage
  }

  // ---- epilogue: merge l across hi halves; write bf16 partial slot ----
  const float lt = lrow + __shfl_xor(lrow, 32);

  char* slot = Ws + ((size_t)b * TOTC + u) * SLOT_B;
  const int row = 32 * w + ql;
  #pragma unroll
  for (int dt = 0; dt < 2; ++dt)
    #pragma unroll
    for (int r1 = 0; r1 < 4; ++r1) {
      u32x2 p;
      p[0] = pk2(acc[dt][4 * r1 + 0], acc[dt][4 * r1 + 1]);
      p[1] = pk2(acc[dt][4 * r1 + 2], acc[dt][4 * r1 + 3]);
      *(u32x2*)(slot + row * 128 + (32 * dt + 8 * r1 + 4 * hi) * 2) = p;
    }
  if (hi == 0) {
    ((float*)(slot + 16384))[row]       = mrow;
    ((float*)(slot + 16384 + 512))[row] = lt;
  }
}

__global__ __launch_bounds__(256, 8) void fattn_merge(
    const char* __restrict__ Ws, float* __restrict__ Og, int CL, int TOTC)
{
  const int blk = blockIdx.x;            // 512 = 128 qb * 4 quarters
  const int qbi = blk >> 2;
  const int qr  = blk & 3;
  const int Qb  = qbi & (NQB - 1);
  const int b   = qbi >> 5;
  const int tid = threadIdx.x;
  const int row = 32 * qr + (tid >> 3);  // q row within 128-block
  const int d0  = (tid & 7) * 8;         // 8 d-elems per thread

  const int ntt    = 2 * Qb + 2;
  const int nvalid = (ntt + CL - 1) / CL;
  int pre = 0;
  for (int q = 0; q < Qb; ++q) pre += (2 * q + 2 + CL - 1) / CL;

  const char* base = Ws + ((size_t)b * TOTC + pre) * SLOT_B;

  float mstar = -INFINITY;
  #pragma unroll 4
  for (int ci = 0; ci < nvalid; ++ci)
    mstar = fmaxf(mstar, ((const float*)(base + (size_t)ci * SLOT_B + 16384))[row]);

  float lsum = 0.f;
  float o[8];
  #pragma unroll
  for (int k = 0; k < 8; ++k) o[k] = 0.f;

  #pragma unroll 4
  for (int ci = 0; ci < nvalid; ++ci) {
    const char* slot = base + (size_t)ci * SLOT_B;
    const float wgt = __expf(((const float*)(slot + 16384))[row] - mstar);
    lsum += wgt * ((const float*)(slot + 16384 + 512))[row];
    const s16x8 ov = *(const s16x8*)(slot + row * 128 + d0 * 2);
    #pragma unroll
    for (int k = 0; k < 8; ++k) o[k] += wgt * bf2f(ov[k]);
  }

  const float inv = 1.0f / lsum;
  float* op = Og + ((size_t)(b * S_LEN + Qb * QBLK + row)) * D_DIM + d0;
  f32x4 o0, o1;
  #pragma unroll
  for (int k = 0; k < 4; ++k) { o0[k] = o[k] * inv; o1[k] = o[4 + k] * inv; }
  *(f32x4*)(op) = o0;
  *(f32x4*)(op + 4) = o1;
}

extern "C" void kernel_launch(void* const* d_in, const int* in_sizes, int n_in,
                              void* d_out, int out_size, void* d_ws, size_t ws_size,
                              hipStream_t stream) {
  const float* Q = (const float*)d_in[0];
  const float* K = (const float*)d_in[1];
  const float* V = (const float*)d_in[2];
  const unsigned char* P = (const unsigned char*)d_in[3];
  float* O  = (float*)d_out;
  char*  Ws = (char*)d_ws;

  // CL=6: measured optimum (4:54.6 / 5:54.0 / 6:48.7 / 8:52.9 us).
  int CL = 6;
  int TOTC = 0;
  for (int q = 0; q < NQB; ++q) TOTC += (2 * q + 2 + CL - 1) / CL;   // 187
  if (ws_size < (size_t)NBATCH * TOTC * SLOT_B) {
    CL = 8;
    TOTC = 0;
    for (int q = 0; q < NQB; ++q) TOTC += (2 * q + 2 + CL - 1) / CL; // 144
  }

  dim3 grid(NBATCH * TOTC);
  dim3 block(256);
  hipLaunchKernelGGL(fattn_partial, grid, block, 0, stream, Q, K, V, P, Ws,
                     CL, TOTC);
  hipLaunchKernelGGL(fattn_merge, dim3(NBATCH * NQB * 4), dim3(256), 0, stream,
                     Ws, O, CL, TOTC);
}

// Round 27
// 48.250 us; speedup vs baseline: 1.1360x; 1.1360x over previous
//
#include <hip/hip_runtime.h>
#include <hip/hip_bf16.h>

// Flash attention fwd, causal + key-padding, B=4 S=4096 D=64, fp32 in/out.
// FINAL (= round 25, the measured optimum, 48.4us; round 26's V-hoist at
// (256,2) cut residency 2.9->2 blocks/CU and regressed — both variants of
// the hoist are now excluded: (256,3) spills, (256,2) loses TLP).
//  - split-KV flash attention: partial kernel over uniform CL=6-tile
//    chunks (heavy-first dispatch), merge kernel combines (bf16 O slots,
//    fp32 m/l, unroll-4 slot walk).
//  - 32x32x16 swapped-operand MFMA (S^T = K.Q^T, O^T = V^T.P^T): softmax
//    fully in-register (lane = q column), tree max + 4-way sum, cross-half
//    merges via __shfl_xor(.,32).
//  - K staged [n][d] bf16 FK-swizzled; V^T staged [d][perm k] with columns
//    permuted into the MFMA C/D-native k-order => PV A-fragment is ONE
//    aligned ds_read_b128 (store+load use the same bijection => exact).
//  - bf16-at-load prefetch (register double-buffer), single-buffer LDS,
//    in-lane V 4x4 transpose, QK-pair hoist, s_setprio on MFMA clusters.
// CL curve measured: 4->54.6, 5->54.0, 6->48.7/48.4, 8->52.9 us.

#define S_LEN 4096
#define D_DIM 64
#define NBATCH 4
#define QBLK 128
#define KVBLK 64
#define NQB (S_LEN / QBLK)          // 32 q-blocks per batch
#define SLOT_B 17408                // 16K bf16 O + 1K fp32 m/l

typedef __attribute__((ext_vector_type(16))) float f32x16;
typedef __attribute__((ext_vector_type(4))) float f32x4;
typedef __attribute__((ext_vector_type(8))) short s16x8;
typedef __attribute__((ext_vector_type(4))) short s16x4;
typedef __attribute__((ext_vector_type(2))) unsigned int u32x2;

#define FK(n) ((((n) ^ ((n) >> 3)) & 7) << 4)   // row swizzle (K and V^T)

__device__ __forceinline__ unsigned short f2bfu(float f) {
  return __builtin_bit_cast(unsigned short, __float2bfloat16(f));
}
__device__ __forceinline__ unsigned pk2(float a, float b) {
  return (unsigned)f2bfu(a) | ((unsigned)f2bfu(b) << 16);
}
__device__ __forceinline__ float bf2f(short s) {
  return __builtin_bit_cast(float, ((unsigned)(unsigned short)s) << 16);
}

__global__ __launch_bounds__(256, 3) void fattn_partial(
    const float* __restrict__ Qg, const float* __restrict__ Kg,
    const float* __restrict__ Vg, const unsigned char* __restrict__ Pad,
    char* __restrict__ Ws, int CL, int TOTC)
{
  // Uniform partition: enumeration index u -> (Qb, ci); heavy-first.
  const int wid = blockIdx.x;
  const int b   = wid & 3;
  const int u   = TOTC - 1 - (wid >> 2);
  int Qb = 0, ci = 0;
  {
    int uu = u, q = 0;
    while (true) {
      const int nch = (2 * q + 2 + CL - 1) / CL;
      if (uu < nch) { ci = uu; break; }
      uu -= nch; ++q;
    }
    Qb = q;
  }
  const int q0  = Qb * QBLK;
  const int ntt = 2 * Qb + 2;
  const int t0  = ci * CL;
  const int t1  = (t0 + CL < ntt) ? (t0 + CL) : ntt;

  const int tid = threadIdx.x;
  const int w   = tid >> 6;          // wave 0..3 -> q rows [q0+32w, q0+32w+32)
  const int l   = tid & 63;
  const int ql  = l & 31;
  const int hi  = l >> 5;
  const int qw0 = q0 + 32 * w;
  const int qa  = qw0 + ql;

  // K staging roles (64 rows x 16-float windows over 256 threads)
  const int sq  = l & 3;
  const int sm  = (l >> 2) & 3;
  const int sc2 = l >> 4;
  const int snb = 4 * w + 16 * sc2;  // n-chunk base (multiple of 4)
  // V staging roles: one 4x4 block per thread (in-lane transpose)
  const int vn0 = (tid & 15) << 2;   // V rows (k values) [vn0, vn0+4)
  const int vd0 = (tid >> 4) << 2;   // V cols (d values) [vd0, vd0+4)
  // k->position permutation: swap 4-groups 1<->2 within each 16-group
  const int pvn0 = (vn0 & 48) | (((vn0 & 4) << 1) | ((vn0 & 8) >> 1));

  __shared__ __align__(16) short Ksh[KVBLK * D_DIM];   // [n][d], FK-swizzled
  __shared__ __align__(16) short Vtsh[D_DIM * KVBLK];  // [d][perm k], FK-swz
  __shared__ int anyPadSh;

  const size_t bS = (size_t)b * S_LEN;
  const unsigned char* PadB = Pad + bS;

  // ---- prologue: block-wide padding flag for this chunk's key range ----
  if (tid == 0) anyPadSh = 0;
  __syncthreads();
  {
    const int nk  = (t1 - t0) * KVBLK;      // <= 512
    const int idx = 2 * tid;
    if (idx < nk) {
      const unsigned char* pp = PadB + t0 * KVBLK + idx;
      const bool nz = pp[0] || ((idx + 1 < nk) ? pp[1] : (unsigned char)0);
      if (nz) anyPadSh = 1;                 // benign same-value race
    }
  }

  // ---- Q fragments (B-operand), pre-scaled by 1/8 ----
  s16x8 qf[4];
  {
    const float* qp = Qg + (bS + qa) * D_DIM + 8 * hi;
    #pragma unroll
    for (int dc = 0; dc < 4; ++dc)
      #pragma unroll
      for (int j = 0; j < 8; ++j)
        qf[dc][j] = (short)f2bfu(qp[16 * dc + j] * 0.125f);
  }

  f32x16 acc[2];
  #pragma unroll
  for (int dt = 0; dt < 2; ++dt)
    #pragma unroll
    for (int i = 0; i < 16; ++i) acc[dt][i] = 0.f;
  float mrow = -INFINITY;
  float lrow = 0.f;

  u32x2 kpb[4], vpb[4];   // bf16-packed prefetch; vpb already transposed

#define LOAD_KV(T) do {                                                      \
    const int kv0_ = (T) * KVBLK;                                            \
    _Pragma("unroll")                                                        \
    for (int s_ = 0; s_ < 4; ++s_) {                                         \
      const size_t go_ =                                                     \
          (bS + kv0_ + snb + sq) * D_DIM + 16 * s_ + 4 * sm;                 \
      const float4 kx = *(const float4*)(Kg + go_);                          \
      kpb[s_][0] = pk2(kx.x, kx.y); kpb[s_][1] = pk2(kx.z, kx.w);            \
    }                                                                        \
    const float* vp_ = Vg + (bS + kv0_ + vn0) * D_DIM + vd0;                 \
    const float4 r0 = *(const float4*)(vp_);                                 \
    const float4 r1 = *(const float4*)(vp_ + D_DIM);                         \
    const float4 r2 = *(const float4*)(vp_ + 2 * D_DIM);                     \
    const float4 r3 = *(const float4*)(vp_ + 3 * D_DIM);                     \
    const float* f0 = (const float*)&r0; const float* f1 = (const float*)&r1;\
    const float* f2 = (const float*)&r2; const float* f3 = (const float*)&r3;\
    _Pragma("unroll")                                                        \
    for (int j_ = 0; j_ < 4; ++j_) {                                         \
      vpb[j_][0] = pk2(f0[j_], f1[j_]);                                      \
      vpb[j_][1] = pk2(f2[j_], f3[j_]);                                      \
    }                                                                        \
  } while (0)

#define STAGE() do {                                                         \
    _Pragma("unroll")                                                        \
    for (int s_ = 0; s_ < 4; ++s_) {                                         \
      const int d0_ = 16 * s_ + 4 * sm; const int nk_ = snb + sq;            \
      *(u32x2*)((char*)&Ksh[0] + nk_ * 128 + ((2 * d0_) ^ FK(nk_))) =        \
          kpb[s_];                                                           \
      const int dv_ = vd0 + s_;                                              \
      *(u32x2*)((char*)&Vtsh[0] + dv_ * 128 + ((2 * pvn0) ^ FK(dv_))) =      \
          vpb[s_];                                                           \
    }                                                                        \
  } while (0)

  LOAD_KV(t0);

  for (int t = t0; t < t1; ++t) {
    STAGE();                          // write prefetched tile to LDS
    __syncthreads();                  // staging visible to all waves
    const bool more = (t + 1 < t1);
    if (more) LOAD_KV(t + 1);         // prefetch next tile into regs

    const int kv0 = t * KVBLK;

    // ---- BOTH QK^T clusters first (sm(0) overlaps QK(1) latency) ----
    f32x16 sv0, sv1;
    __builtin_amdgcn_s_setprio(1);
    {
      f32x16 a;
      #pragma unroll
      for (int i = 0; i < 16; ++i) a[i] = 0.f;
      #pragma unroll
      for (int dc = 0; dc < 4; ++dc) {
        const int nr = ql;
        const s16x8 kf = *(const s16x8*)((char*)&Ksh[0] + nr * 128 +
                                         ((32 * dc + 16 * hi) ^ FK(nr)));
        a = __builtin_amdgcn_mfma_f32_32x32x16_bf16(kf, qf[dc], a, 0, 0, 0);
      }
      sv0 = a;
    }
    {
      f32x16 a;
      #pragma unroll
      for (int i = 0; i < 16; ++i) a[i] = 0.f;
      #pragma unroll
      for (int dc = 0; dc < 4; ++dc) {
        const int nr = 32 + ql;
        const s16x8 kf = *(const s16x8*)((char*)&Ksh[0] + nr * 128 +
                                         ((32 * dc + 16 * hi) ^ FK(nr)));
        a = __builtin_amdgcn_mfma_f32_32x32x16_bf16(kf, qf[dc], a, 0, 0, 0);
      }
      sv1 = a;
    }
    __builtin_amdgcn_s_setprio(0);

    // ---- per-32k subtile: mask -> online softmax -> PV ----
    #pragma unroll
    for (int kt = 0; kt < 2; ++kt) {
      f32x16 sv = (kt == 0) ? sv0 : sv1;
      const int kvt = kv0 + 32 * kt;
      // padding (rare path)
      if (anyPadSh) {
        #pragma unroll
        for (int r1 = 0; r1 < 4; ++r1) {
          const unsigned pd =
              *(const unsigned*)(PadB + kvt + 8 * r1 + 4 * hi);
          #pragma unroll
          for (int r0 = 0; r0 < 4; ++r0)
            if ((pd >> (8 * r0)) & 0xFFu) sv[4 * r1 + r0] = -1e30f;
        }
      }
      // causal mask (diagonal band only): k = kvt+8r1+4hi+r0
      if (kvt + 31 > qw0) {
        #pragma unroll
        for (int r1 = 0; r1 < 4; ++r1)
          #pragma unroll
          for (int r0 = 0; r0 < 4; ++r0)
            if (kvt + 8 * r1 + 4 * hi + r0 > qa) sv[4 * r1 + r0] = -1e30f;
      }

      // online softmax step (tree max, 4-way sum)
      f32x4 m4;
      #pragma unroll
      for (int i = 0; i < 4; ++i)
        m4[i] = fmaxf(fmaxf(sv[i], sv[i + 4]), fmaxf(sv[i + 8], sv[i + 12]));
      float vm = fmaxf(fmaxf(m4[0], m4[1]), fmaxf(m4[2], m4[3]));
      vm = fmaxf(vm, __shfl_xor(vm, 32));         // merge across hi halves
      const float mn   = fmaxf(mrow, vm);
      const float corr = __expf(mrow - mn);
      mrow = mn;
      lrow *= corr;
      #pragma unroll
      for (int dt = 0; dt < 2; ++dt)
        #pragma unroll
        for (int i = 0; i < 16; ++i) acc[dt][i] *= corr;

      float rs0 = 0.f, rs1 = 0.f, rs2 = 0.f, rs3 = 0.f;
      #pragma unroll
      for (int i4 = 0; i4 < 16; i4 += 4) {
        const float p0 = __expf(sv[i4 + 0] - mn);
        const float p1 = __expf(sv[i4 + 1] - mn);
        const float p2 = __expf(sv[i4 + 2] - mn);
        const float p3 = __expf(sv[i4 + 3] - mn);
        sv[i4 + 0] = p0; sv[i4 + 1] = p1;
        sv[i4 + 2] = p2; sv[i4 + 3] = p3;
        rs0 += p0; rs1 += p1; rs2 += p2; rs3 += p3;
      }
      lrow += (rs0 + rs1) + (rs2 + rs3);          // own half-sum only

      // O^T += mfma(A=V^T, B=P): permuted columns -> one ds_read_b128
      __builtin_amdgcn_s_setprio(1);
      #pragma unroll
      for (int sh = 0; sh < 2; ++sh) {
        const int sk = 2 * kt + sh;
        const int rb = 8 * sh;
        union { unsigned uu[4]; s16x8 v; } pb;
        pb.uu[0] = pk2(sv[rb + 0], sv[rb + 1]);
        pb.uu[1] = pk2(sv[rb + 2], sv[rb + 3]);
        pb.uu[2] = pk2(sv[rb + 4], sv[rb + 5]);
        pb.uu[3] = pk2(sv[rb + 6], sv[rb + 7]);
        #pragma unroll
        for (int dt = 0; dt < 2; ++dt) {
          const int dr = 32 * dt + ql;
          const s16x8 vf = *(const s16x8*)((char*)&Vtsh[0] + dr * 128 +
                                           ((32 * sk + 16 * hi) ^ FK(dr)));
          acc[dt] = __builtin_amdgcn_mfma_f32_32x32x16_bf16(vf, pb.v, acc[dt], 0, 0, 0);
        }
      }
      __builtin_amdgcn_s_setprio(0);
    }

    __syncthreads();                  // all waves done reading before restage
  }

  // ---- epilogue: merge l across hi halves; write bf16 partial slot ----
  const float lt = lrow + __shfl_xor(lrow, 32);

  char* slot = Ws + ((size_t)b * TOTC + u) * SLOT_B;
  const int row = 32 * w + ql;
  #pragma unroll
  for (int dt = 0; dt < 2; ++dt)
    #pragma unroll
    for (int r1 = 0; r1 < 4; ++r1) {
      u32x2 p;
      p[0] = pk2(acc[dt][4 * r1 + 0], acc[dt][4 * r1 + 1]);
      p[1] = pk2(acc[dt][4 * r1 + 2], acc[dt][4 * r1 + 3]);
      *(u32x2*)(slot + row * 128 + (32 * dt + 8 * r1 + 4 * hi) * 2) = p;
    }
  if (hi == 0) {
    ((float*)(slot + 16384))[row]       = mrow;
    ((float*)(slot + 16384 + 512))[row] = lt;
  }
}

__global__ __launch_bounds__(256, 8) void fattn_merge(
    const char* __restrict__ Ws, float* __restrict__ Og, int CL, int TOTC)
{
  const int blk = blockIdx.x;            // 512 = 128 qb * 4 quarters
  const int qbi = blk >> 2;
  const int qr  = blk & 3;
  const int Qb  = qbi & (NQB - 1);
  const int b   = qbi >> 5;
  const int tid = threadIdx.x;
  const int row = 32 * qr + (tid >> 3);  // q row within 128-block
  const int d0  = (tid & 7) * 8;         // 8 d-elems per thread

  const int ntt    = 2 * Qb + 2;
  const int nvalid = (ntt + CL - 1) / CL;
  int pre = 0;
  for (int q = 0; q < Qb; ++q) pre += (2 * q + 2 + CL - 1) / CL;

  const char* base = Ws + ((size_t)b * TOTC + pre) * SLOT_B;

  float mstar = -INFINITY;
  #pragma unroll 4
  for (int ci = 0; ci < nvalid; ++ci)
    mstar = fmaxf(mstar, ((const float*)(base + (size_t)ci * SLOT_B + 16384))[row]);

  float lsum = 0.f;
  float o[8];
  #pragma unroll
  for (int k = 0; k < 8; ++k) o[k] = 0.f;

  #pragma unroll 4
  for (int ci = 0; ci < nvalid; ++ci) {
    const char* slot = base + (size_t)ci * SLOT_B;
    const float wgt = __expf(((const float*)(slot + 16384))[row] - mstar);
    lsum += wgt * ((const float*)(slot + 16384 + 512))[row];
    const s16x8 ov = *(const s16x8*)(slot + row * 128 + d0 * 2);
    #pragma unroll
    for (int k = 0; k < 8; ++k) o[k] += wgt * bf2f(ov[k]);
  }

  const float inv = 1.0f / lsum;
  float* op = Og + ((size_t)(b * S_LEN + Qb * QBLK + row)) * D_DIM + d0;
  f32x4 o0, o1;
  #pragma unroll
  for (int k = 0; k < 4; ++k) { o0[k] = o[k] * inv; o1[k] = o[4 + k] * inv; }
  *(f32x4*)(op) = o0;
  *(f32x4*)(op + 4) = o1;
}

extern "C" void kernel_launch(void* const* d_in, const int* in_sizes, int n_in,
                              void* d_out, int out_size, void* d_ws, size_t ws_size,
                              hipStream_t stream) {
  const float* Q = (const float*)d_in[0];
  const float* K = (const float*)d_in[1];
  const float* V = (const float*)d_in[2];
  const unsigned char* P = (const unsigned char*)d_in[3];
  float* O  = (float*)d_out;
  char*  Ws = (char*)d_ws;

  // CL=6: measured optimum (4:54.6 / 5:54.0 / 6:48.4 / 8:52.9 us).
  // 748 blocks ~ 2.92 blocks/CU fills 3 residency rounds almost exactly.
  int CL = 6;
  int TOTC = 0;
  for (int q = 0; q < NQB; ++q) TOTC += (2 * q + 2 + CL - 1) / CL;   // 187
  if (ws_size < (size_t)NBATCH * TOTC * SLOT_B) {
    CL = 8;
    TOTC = 0;
    for (int q = 0; q < NQB; ++q) TOTC += (2 * q + 2 + CL - 1) / CL; // 144
  }

  dim3 grid(NBATCH * TOTC);
  dim3 block(256);
  hipLaunchKernelGGL(fattn_partial, grid, block, 0, stream, Q, K, V, P, Ws,
                     CL, TOTC);
  hipLaunchKernelGGL(fattn_merge, dim3(NBATCH * NQB * 4), dim3(256), 0, stream,
                     Ws, O, CL, TOTC);
}